// Round 1
// 1007.943 us; speedup vs baseline: 1.3164x; 1.3164x over previous
//
#include <hip/hip_runtime.h>
#include <hip/hip_bf16.h>
#include <cstddef>

#define N_USERS 50000
#define N_ITEMS 10000
#define N_NODES 100000
#define EMB 64
#define NNZ_E 1600000
#define VIS_DIM 2048
#define TXT_DIM 300

typedef short bf16x8 __attribute__((ext_vector_type(8)));
typedef float f32x4  __attribute__((ext_vector_type(4)));

__device__ inline unsigned short f2bf(float x) {
    __hip_bfloat16 h = __float2bfloat16(x);
    return __builtin_bit_cast(unsigned short, h);
}
__device__ inline float bf2f(unsigned short u) {
    unsigned int t = ((unsigned int)u) << 16;
    float f;
    __builtin_memcpy(&f, &t, 4);
    return f;
}

// ---------------------------------------------------------------------------
// Split-precision bf16 MFMA GEMM v2: C[M,N] = act(A[M,K] @ W[N,K]^T + bias).
// TM=128, TN=128, BK=32. 256 threads = 4 waves in 2x2, each wave 64x64 as
// 4x4 frags of mfma_f32_16x16x32_bf16, 3-term split (Ah*Wh + Ah*Wl + Al*Wh).
// Register-prefetch pipeline: global loads for k0+1 issued before the MFMA
// block so memory latency overlaps compute.
// LDS rows padded 32->40 shorts (80 B).
// ---------------------------------------------------------------------------
#define GLDW 40

__global__ __launch_bounds__(256, 2) void gemm_bf3(
    const float* __restrict__ A, const float* __restrict__ W,
    const float* __restrict__ bias, float* __restrict__ C,
    int M, int N, int K, int relu)
{
    __shared__ unsigned short Ah[128][GLDW], Al[128][GLDW];
    __shared__ unsigned short Wh[128][GLDW], Wl[128][GLDW];

    const int t   = threadIdx.x;
    const int w   = t >> 6;
    const int l   = t & 63;
    const int l16 = l & 15;
    const int lq  = l >> 4;
    const int m0  = blockIdx.y * 128;
    const int n0  = blockIdx.x * 128;
    const int mh  = (w & 1) * 64;
    const int nh  = (w >> 1) * 64;

    // staging chunk map: chunk c (0..511) per matrix: row = c>>2, kc = c&3
    // thread t owns chunks {t, t+256}; 8 consecutive k-elements per chunk.
    const int r0 = t >> 2,          kc0 = t & 3;
    const int r1 = (t + 256) >> 2,  kc1 = t & 3;   // (t+256)&3 == t&3

    f32x4 acc[4][4] = {};

    const int kiters = (K + 31) / 32;

    float pa[2][8], pw[2][8];

    // ---- prologue: load tile 0 into regs ----
    {
        const int k0 = 0;
        #pragma unroll
        for (int p = 0; p < 2; p++) {
            int row = p ? r1 : r0, kc = p ? kc1 : kc0;
            int rg = m0 + row; if (rg >= M) rg = M - 1;
            const float* g = A + (size_t)rg * K + k0 + kc * 8;
            if (k0 + kc * 8 + 7 < K) {
                float4 q0 = *(const float4*)g, q1 = *(const float4*)(g + 4);
                pa[p][0]=q0.x; pa[p][1]=q0.y; pa[p][2]=q0.z; pa[p][3]=q0.w;
                pa[p][4]=q1.x; pa[p][5]=q1.y; pa[p][6]=q1.z; pa[p][7]=q1.w;
            } else {
                #pragma unroll
                for (int i = 0; i < 8; i++)
                    pa[p][i] = (k0 + kc * 8 + i < K) ? g[i] : 0.f;
            }
            int ng = n0 + row; if (ng >= N) ng = N - 1;
            const float* gw = W + (size_t)ng * K + k0 + kc * 8;
            if (k0 + kc * 8 + 7 < K) {
                float4 q0 = *(const float4*)gw, q1 = *(const float4*)(gw + 4);
                pw[p][0]=q0.x; pw[p][1]=q0.y; pw[p][2]=q0.z; pw[p][3]=q0.w;
                pw[p][4]=q1.x; pw[p][5]=q1.y; pw[p][6]=q1.z; pw[p][7]=q1.w;
            } else {
                #pragma unroll
                for (int i = 0; i < 8; i++)
                    pw[p][i] = (k0 + kc * 8 + i < K) ? gw[i] : 0.f;
            }
        }
    }

    for (int kt = 0; kt < kiters; kt++) {
        // ---- convert prefetched regs -> LDS hi/lo ----
        #pragma unroll
        for (int p = 0; p < 2; p++) {
            int row = p ? r1 : r0, kc = p ? kc1 : kc0;
            bf16x8 hi, lo;
            #pragma unroll
            for (int i = 0; i < 8; i++) {
                unsigned short h = f2bf(pa[p][i]);
                hi[i] = (short)h;
                lo[i] = (short)f2bf(pa[p][i] - bf2f(h));
            }
            *(bf16x8*)&Ah[row][kc * 8] = hi;
            *(bf16x8*)&Al[row][kc * 8] = lo;
            #pragma unroll
            for (int i = 0; i < 8; i++) {
                unsigned short h = f2bf(pw[p][i]);
                hi[i] = (short)h;
                lo[i] = (short)f2bf(pw[p][i] - bf2f(h));
            }
            *(bf16x8*)&Wh[row][kc * 8] = hi;
            *(bf16x8*)&Wl[row][kc * 8] = lo;
        }
        __syncthreads();

        // ---- issue next tile's global loads (overlap with MFMA below) ----
        if (kt + 1 < kiters) {
            const int k0 = (kt + 1) * 32;
            #pragma unroll
            for (int p = 0; p < 2; p++) {
                int row = p ? r1 : r0, kc = p ? kc1 : kc0;
                int rg = m0 + row; if (rg >= M) rg = M - 1;
                const float* g = A + (size_t)rg * K + k0 + kc * 8;
                if (k0 + kc * 8 + 7 < K) {
                    float4 q0 = *(const float4*)g, q1 = *(const float4*)(g + 4);
                    pa[p][0]=q0.x; pa[p][1]=q0.y; pa[p][2]=q0.z; pa[p][3]=q0.w;
                    pa[p][4]=q1.x; pa[p][5]=q1.y; pa[p][6]=q1.z; pa[p][7]=q1.w;
                } else {
                    #pragma unroll
                    for (int i = 0; i < 8; i++)
                        pa[p][i] = (k0 + kc * 8 + i < K) ? g[i] : 0.f;
                }
                int ng = n0 + row; if (ng >= N) ng = N - 1;
                const float* gw = W + (size_t)ng * K + k0 + kc * 8;
                if (k0 + kc * 8 + 7 < K) {
                    float4 q0 = *(const float4*)gw, q1 = *(const float4*)(gw + 4);
                    pw[p][0]=q0.x; pw[p][1]=q0.y; pw[p][2]=q0.z; pw[p][3]=q0.w;
                    pw[p][4]=q1.x; pw[p][5]=q1.y; pw[p][6]=q1.z; pw[p][7]=q1.w;
                } else {
                    #pragma unroll
                    for (int i = 0; i < 8; i++)
                        pw[p][i] = (k0 + kc * 8 + i < K) ? gw[i] : 0.f;
                }
            }
        }

        // ---- MFMA: 4x4 frags x 3 split terms ----
        {
            bf16x8 ah[4], al[4];
            #pragma unroll
            for (int mi = 0; mi < 4; mi++) {
                ah[mi] = *(const bf16x8*)&Ah[mh + mi * 16 + l16][lq * 8];
                al[mi] = *(const bf16x8*)&Al[mh + mi * 16 + l16][lq * 8];
            }
            #pragma unroll
            for (int ni = 0; ni < 4; ni++) {
                bf16x8 bh = *(const bf16x8*)&Wh[nh + ni * 16 + l16][lq * 8];
                bf16x8 bl = *(const bf16x8*)&Wl[nh + ni * 16 + l16][lq * 8];
                #pragma unroll
                for (int mi = 0; mi < 4; mi++) {
                    acc[mi][ni] = __builtin_amdgcn_mfma_f32_16x16x32_bf16(
                        ah[mi], bh, acc[mi][ni], 0, 0, 0);
                    acc[mi][ni] = __builtin_amdgcn_mfma_f32_16x16x32_bf16(
                        ah[mi], bl, acc[mi][ni], 0, 0, 0);
                    acc[mi][ni] = __builtin_amdgcn_mfma_f32_16x16x32_bf16(
                        al[mi], bh, acc[mi][ni], 0, 0, 0);
                }
            }
        }
        __syncthreads();
    }

    // ---- epilogue ----
    #pragma unroll
    for (int ni = 0; ni < 4; ni++) {
        int col = n0 + nh + ni * 16 + l16;
        float bcol = bias[col];
        #pragma unroll
        for (int mi = 0; mi < 4; mi++) {
            #pragma unroll
            for (int r = 0; r < 4; r++) {
                int row = m0 + mh + mi * 16 + lq * 4 + r;
                if (row >= M) continue;
                float v = acc[mi][ni][r] + bcol;
                if (relu) v = fmaxf(v, 0.f);
                C[(size_t)row * N + col] = v;
            }
        }
    }
}

// ---------------------------------------------------------------------------
__global__ void transp64(const float* __restrict__ W, float* __restrict__ wT, int K)
{
    int i = blockIdx.x * 256 + threadIdx.x;
    if (i >= 64 * K) return;
    int d = i / K, k = i - d * K;
    wT[k * 64 + d] = W[i];
}

// ---------------------------------------------------------------------------
// linear64 v2: out[M,64] = in[M,K] @ wT[K,64] * in_scale + bias  (opt. +=)
// 4 rows per wave, 16 rows per block. Inner loop: k-step 8 with float4
// broadcast x-loads (2 per row) + 8 coalesced wT loads, 4 independent
// accumulators -> ~16 loads in flight instead of 2 dependent scalar loads.
// Fixes the 199us latency-bound v1 (VGPR=8, VALUBusy 16%, 66 GB/s).
// Requires K % 8 == 0 (holds: 512/256/64).
// ---------------------------------------------------------------------------
__global__ __launch_bounds__(256) void linear64(
    const float* __restrict__ in, const float* __restrict__ wT,
    const float* __restrict__ bias, float* __restrict__ out,
    int M, int K, float in_scale, int add)
{
    int t  = threadIdx.x;
    int d  = t & 63;
    int w  = t >> 6;
    int m0 = blockIdx.x * 16 + w * 4;
    if (m0 >= M) return;
    int mlast = M - 1;
    int m1 = (m0 + 1 < M) ? m0 + 1 : mlast;
    int m2 = (m0 + 2 < M) ? m0 + 2 : mlast;
    int m3 = (m0 + 3 < M) ? m0 + 3 : mlast;

    const float* x0 = in + (size_t)m0 * K;
    const float* x1 = in + (size_t)m1 * K;
    const float* x2 = in + (size_t)m2 * K;
    const float* x3 = in + (size_t)m3 * K;

    float a0 = 0.f, a1 = 0.f, a2 = 0.f, a3 = 0.f;

    for (int k = 0; k < K; k += 8) {
        const float* wp = wT + (size_t)k * 64 + d;
        float w0 = wp[0],   w1 = wp[64],  w2 = wp[128], w3 = wp[192];
        float w4 = wp[256], w5 = wp[320], w6 = wp[384], w7 = wp[448];
        float4 p0 = *(const float4*)(x0 + k), q0 = *(const float4*)(x0 + k + 4);
        float4 p1 = *(const float4*)(x1 + k), q1 = *(const float4*)(x1 + k + 4);
        float4 p2 = *(const float4*)(x2 + k), q2 = *(const float4*)(x2 + k + 4);
        float4 p3 = *(const float4*)(x3 + k), q3 = *(const float4*)(x3 + k + 4);
        a0 += p0.x*w0 + p0.y*w1 + p0.z*w2 + p0.w*w3
            + q0.x*w4 + q0.y*w5 + q0.z*w6 + q0.w*w7;
        a1 += p1.x*w0 + p1.y*w1 + p1.z*w2 + p1.w*w3
            + q1.x*w4 + q1.y*w5 + q1.z*w6 + q1.w*w7;
        a2 += p2.x*w0 + p2.y*w1 + p2.z*w2 + p2.w*w3
            + q2.x*w4 + q2.y*w5 + q2.z*w6 + q2.w*w7;
        a3 += p3.x*w0 + p3.y*w1 + p3.z*w2 + p3.w*w3
            + q3.x*w4 + q3.y*w5 + q3.z*w6 + q3.w*w7;
    }

    float b = bias[d];
    float r0 = a0 * in_scale + b;
    float r1 = a1 * in_scale + b;
    float r2 = a2 * in_scale + b;
    float r3 = a3 * in_scale + b;
    if (add) {
        out[(size_t)m0 * 64 + d] += r0;
        if (m0 + 1 < M) out[(size_t)m1 * 64 + d] += r1;
        if (m0 + 2 < M) out[(size_t)m2 * 64 + d] += r2;
        if (m0 + 3 < M) out[(size_t)m3 * 64 + d] += r3;
    } else {
        out[(size_t)m0 * 64 + d] = r0;
        if (m0 + 1 < M) out[(size_t)m1 * 64 + d] = r1;
        if (m0 + 2 < M) out[(size_t)m2 * 64 + d] = r2;
        if (m0 + 3 < M) out[(size_t)m3 * 64 + d] = r3;
    }
}

// ---------------------------------------------------------------------------
__global__ void ego_fill(const float* __restrict__ emb, float* __restrict__ cur0,
                         float* __restrict__ out_full)
{
    int tid = blockIdx.x * 256 + threadIdx.x;
    if (tid >= N_NODES * EMB) return;
    int m = tid >> 6, d = tid & 63;
    float v;
    if (m < N_USERS || m >= N_USERS + N_ITEMS) {
        v = emb[tid];
        cur0[tid] = v;
    } else {
        v = cur0[tid];
    }
    out_full[(size_t)m * 192 + d] = v;
}

// ---------------------------------------------------------------------------
// CSR build: histogram -> exclusive scan -> scatter
// ---------------------------------------------------------------------------
__global__ __launch_bounds__(256) void hist_rows(
    const int* __restrict__ row, int* __restrict__ cnt, int nnz)
{
    int e = blockIdx.x * 256 + threadIdx.x;
    if (e >= nnz) return;
    atomicAdd(&cnt[row[e]], 1);
}

__global__ __launch_bounds__(256) void scan1(int* __restrict__ cnt,
                                             int* __restrict__ bsum, int n)
{
    __shared__ int part[256];
    int t = threadIdx.x;
    int base = blockIdx.x * 1024 + t * 4;
    int v0 = 0, v1 = 0, v2 = 0, v3 = 0;
    if (base + 0 < n) v0 = cnt[base + 0];
    if (base + 1 < n) v1 = cnt[base + 1];
    if (base + 2 < n) v2 = cnt[base + 2];
    if (base + 3 < n) v3 = cnt[base + 3];
    int s = v0 + v1 + v2 + v3;
    part[t] = s;
    __syncthreads();
    for (int off = 1; off < 256; off <<= 1) {
        int x = (t >= off) ? part[t - off] : 0;
        __syncthreads();
        part[t] += x;
        __syncthreads();
    }
    int excl = part[t] - s;
    if (t == 255) bsum[blockIdx.x] = part[t];
    if (base + 0 < n) cnt[base + 0] = excl;
    if (base + 1 < n) cnt[base + 1] = excl + v0;
    if (base + 2 < n) cnt[base + 2] = excl + v0 + v1;
    if (base + 3 < n) cnt[base + 3] = excl + v0 + v1 + v2;
}

__global__ void scan2(int* __restrict__ bsum, int nb)
{
    if (threadIdx.x == 0 && blockIdx.x == 0) {
        int acc = 0;
        for (int i = 0; i < nb; i++) { int v = bsum[i]; bsum[i] = acc; acc += v; }
    }
}

__global__ __launch_bounds__(256) void scan3(
    const int* __restrict__ excl, const int* __restrict__ bsum,
    int* __restrict__ row_ptr, int* __restrict__ row_cur, int n, int nnz)
{
    int i = blockIdx.x * 256 + threadIdx.x;
    if (i > n) return;
    if (i == n) { row_ptr[n] = nnz; return; }
    int v = excl[i] + bsum[i >> 10];
    row_ptr[i] = v;
    row_cur[i] = v;
}

__global__ __launch_bounds__(256) void scatter_csr(
    const int* __restrict__ row, const int* __restrict__ col,
    const float* __restrict__ val, int* __restrict__ row_cur,
    int* __restrict__ col_s, float* __restrict__ val_s, int nnz)
{
    int e = blockIdx.x * 256 + threadIdx.x;
    if (e >= nnz) return;
    int r = row[e];
    int p = atomicAdd(&row_cur[r], 1);
    col_s[p] = col[e];
    val_s[p] = val[e];
}

// ---------------------------------------------------------------------------
// Gather SpMM v2: one wave per row; 64 lanes = 4 edge-slots x 16 dim-groups.
// float4 gathers, 4 edges in flight, shuffle-xor reduce across edge slots.
// ---------------------------------------------------------------------------
__global__ __launch_bounds__(256) void spmm_gather(
    const int* __restrict__ row_ptr, const int* __restrict__ col_s,
    const float* __restrict__ val_s, const float* __restrict__ cur,
    float* __restrict__ nb)
{
    int t  = threadIdx.x;
    int wv = t >> 6;
    int l  = t & 63;
    int eg = l >> 4;          // edge slot 0..3
    int dg = l & 15;          // dim group (4 floats)
    int m = blockIdx.x * 4 + wv;
    if (m >= N_NODES) return;
    int beg = row_ptr[m], end = row_ptr[m + 1];
    float ax = 0.f, ay = 0.f, az = 0.f, aw = 0.f;
    for (int j = beg + eg; j < end; j += 4) {
        int   c = col_s[j];
        float v = val_s[j];
        float4 cv = *(const float4*)&cur[(size_t)c * 64 + dg * 4];
        ax += v * cv.x; ay += v * cv.y; az += v * cv.z; aw += v * cv.w;
    }
    ax += __shfl_xor(ax, 16, 64); ay += __shfl_xor(ay, 16, 64);
    az += __shfl_xor(az, 16, 64); aw += __shfl_xor(aw, 16, 64);
    ax += __shfl_xor(ax, 32, 64); ay += __shfl_xor(ay, 32, 64);
    az += __shfl_xor(az, 32, 64); aw += __shfl_xor(aw, 32, 64);
    if (eg == 0) {
        float4 r; r.x = ax; r.y = ay; r.z = az; r.w = aw;
        *(float4*)&nb[(size_t)m * 64 + dg * 4] = r;
    }
}

// ---------------------------------------------------------------------------
// concat_lin v2: same ILP treatment as linear64 v2 — 4 rows/wave, 16/block,
// float4 x-loads + 8 wT loads per k-step, 4 independent accumulators.
// K = 128 (two 64-halves: cur then nb).
// ---------------------------------------------------------------------------
__global__ __launch_bounds__(256) void concat_lin(
    const float* __restrict__ cur, const float* __restrict__ nb,
    const float* __restrict__ wT, const float* __restrict__ bias,
    float* __restrict__ out_cur, float* __restrict__ out_full, int col_off)
{
    int t  = threadIdx.x;
    int d  = t & 63;
    int w  = t >> 6;
    int m0 = blockIdx.x * 16 + w * 4;
    if (m0 >= N_NODES) return;
    int mlast = N_NODES - 1;
    int m1 = (m0 + 1 < N_NODES) ? m0 + 1 : mlast;
    int m2 = (m0 + 2 < N_NODES) ? m0 + 2 : mlast;
    int m3 = (m0 + 3 < N_NODES) ? m0 + 3 : mlast;

    float a0 = 0.f, a1 = 0.f, a2 = 0.f, a3 = 0.f;

    #pragma unroll
    for (int half = 0; half < 2; half++) {
        const float* src = half ? nb : cur;
        const float* wph = wT + (size_t)half * 64 * 64;
        const float* x0 = src + (size_t)m0 * 64;
        const float* x1 = src + (size_t)m1 * 64;
        const float* x2 = src + (size_t)m2 * 64;
        const float* x3 = src + (size_t)m3 * 64;
        #pragma unroll
        for (int k = 0; k < 64; k += 8) {
            const float* wp = wph + (size_t)k * 64 + d;
            float w0 = wp[0],   w1 = wp[64],  w2 = wp[128], w3 = wp[192];
            float w4 = wp[256], w5 = wp[320], w6 = wp[384], w7 = wp[448];
            float4 p0 = *(const float4*)(x0 + k), q0 = *(const float4*)(x0 + k + 4);
            float4 p1 = *(const float4*)(x1 + k), q1 = *(const float4*)(x1 + k + 4);
            float4 p2 = *(const float4*)(x2 + k), q2 = *(const float4*)(x2 + k + 4);
            float4 p3 = *(const float4*)(x3 + k), q3 = *(const float4*)(x3 + k + 4);
            a0 += p0.x*w0 + p0.y*w1 + p0.z*w2 + p0.w*w3
                + q0.x*w4 + q0.y*w5 + q0.z*w6 + q0.w*w7;
            a1 += p1.x*w0 + p1.y*w1 + p1.z*w2 + p1.w*w3
                + q1.x*w4 + q1.y*w5 + q1.z*w6 + q1.w*w7;
            a2 += p2.x*w0 + p2.y*w1 + p2.z*w2 + p2.w*w3
                + q2.x*w4 + q2.y*w5 + q2.z*w6 + q2.w*w7;
            a3 += p3.x*w0 + p3.y*w1 + p3.z*w2 + p3.w*w3
                + q3.x*w4 + q3.y*w5 + q3.z*w6 + q3.w*w7;
        }
    }

    float b = bias[d];
    float r0 = a0 + b; r0 = (r0 > 0.f) ? r0 : 0.01f * r0;
    float r1 = a1 + b; r1 = (r1 > 0.f) ? r1 : 0.01f * r1;
    float r2 = a2 + b; r2 = (r2 > 0.f) ? r2 : 0.01f * r2;
    float r3 = a3 + b; r3 = (r3 > 0.f) ? r3 : 0.01f * r3;

    if (out_cur) {
        out_cur[(size_t)m0 * 64 + d] = r0;
        if (m0 + 1 < N_NODES) out_cur[(size_t)m1 * 64 + d] = r1;
        if (m0 + 2 < N_NODES) out_cur[(size_t)m2 * 64 + d] = r2;
        if (m0 + 3 < N_NODES) out_cur[(size_t)m3 * 64 + d] = r3;
    }
    out_full[(size_t)m0 * 192 + col_off + d] = r0;
    if (m0 + 1 < N_NODES) out_full[(size_t)m1 * 192 + col_off + d] = r1;
    if (m0 + 2 < N_NODES) out_full[(size_t)m2 * 192 + col_off + d] = r2;
    if (m0 + 3 < N_NODES) out_full[(size_t)m3 * 192 + col_off + d] = r3;
}

// ---------------------------------------------------------------------------
extern "C" void kernel_launch(void* const* d_in, const int* in_sizes, int n_in,
                              void* d_out, int out_size, void* d_ws, size_t ws_size,
                              hipStream_t stream)
{
    const int*   adj_row = (const int*)  d_in[0];
    const int*   adj_col = (const int*)  d_in[1];
    const float* adj_val = (const float*)d_in[2];
    const float* emb     = (const float*)d_in[3];
    const float* visf    = (const float*)d_in[4];
    const float* txtf    = (const float*)d_in[5];
    const float* Wv1 = (const float*)d_in[6];  const float* bv1 = (const float*)d_in[7];
    const float* Wv2 = (const float*)d_in[8];  const float* bv2 = (const float*)d_in[9];
    const float* Wt1 = (const float*)d_in[10]; const float* bt1 = (const float*)d_in[11];
    const float* Wt2 = (const float*)d_in[12]; const float* bt2 = (const float*)d_in[13];
    const float* Wd  = (const float*)d_in[14]; const float* bd  = (const float*)d_in[15];
    const float* Wc0 = (const float*)d_in[16]; const float* bc0 = (const float*)d_in[17];
    const float* Wc1 = (const float*)d_in[18]; const float* bc1 = (const float*)d_in[19];

    float* out = (float*)d_out;
    float* ws  = (float*)d_ws;

    // workspace layout (float offsets) — unchanged from R2 (proven size)
    float* H1v  = ws + 0;          // 10000*512
    float* H1t  = ws + 5120000;    // 10000*256
    float* nb   = ws + 0;          // 100000*64 (reuses H1v/H1t region)
    float* s    = ws + 7680000;    // 10000*64
    float* cur0 = ws + 8320000;    // 100000*64
    float* cur1 = ws + 14720000;   // 100000*64
    float* wv2T = ws + 21120000;   // 512*64
    float* wt2T = wv2T + 32768;    // 256*64
    float* wdT  = wt2T + 16384;    // 64*64
    float* wc0T = wdT  + 4096;     // 128*64
    float* wc1T = wc0T + 8192;     // 128*64
    int*   col_s   = (int*)  (ws + 21200000);  // 1.6M
    float* val_s   =          ws + 22800000;   // 1.6M
    int*   row_ptr = (int*)  (ws + 24400000);  // 100001
    int*   row_cur = (int*)  (ws + 24510000);  // 100000
    int*   cnt     = (int*)  (ws + 24620000);  // 100000
    int*   bsum    = (int*)  (ws + 24730000);  // 98

    const int NBLK = (N_NODES + 1023) / 1024;  // 98

    // ---- weight transposes (tiny) ----
    transp64<<<(64 * 512 + 255) / 256, 256, 0, stream>>>(Wv2, wv2T, 512);
    transp64<<<(64 * 256 + 255) / 256, 256, 0, stream>>>(Wt2, wt2T, 256);
    transp64<<<(64 * 64  + 255) / 256, 256, 0, stream>>>(Wd,  wdT,  64);
    transp64<<<(64 * 128 + 255) / 256, 256, 0, stream>>>(Wc0, wc0T, 128);
    transp64<<<(64 * 128 + 255) / 256, 256, 0, stream>>>(Wc1, wc1T, 128);

    // ---- CSR build (reused for both propagation layers) ----
    hipMemsetAsync(cnt, 0, N_NODES * sizeof(int), stream);
    hist_rows<<<(NNZ_E + 255) / 256, 256, 0, stream>>>(adj_row, cnt, NNZ_E);
    scan1<<<NBLK, 256, 0, stream>>>(cnt, bsum, N_NODES);
    scan2<<<1, 64, 0, stream>>>(bsum, NBLK);
    scan3<<<(N_NODES + 256) / 256, 256, 0, stream>>>(cnt, bsum, row_ptr, row_cur,
                                                     N_NODES, NNZ_E);
    scatter_csr<<<(NNZ_E + 255) / 256, 256, 0, stream>>>(adj_row, adj_col, adj_val,
                                                         row_cur, col_s, val_s, NNZ_E);

    // ---- item MLP layer 1: pipelined split-bf16 MFMA GEMMs ----
    {
        dim3 g(512 / 128, (N_ITEMS + 127) / 128);
        gemm_bf3<<<g, 256, 0, stream>>>(visf, Wv1, bv1, H1v, N_ITEMS, 512, VIS_DIM, 1);
    }
    {
        dim3 g(256 / 128, (N_ITEMS + 127) / 128);
        gemm_bf3<<<g, 256, 0, stream>>>(txtf, Wt1, bt1, H1t, N_ITEMS, 256, TXT_DIM, 1);
    }

    // ---- layer 2 + shared Wd:  fused = (0.5*(vis2+txt2)) @ Wd^T + bd ----
    linear64<<<(N_ITEMS + 15) / 16, 256, 0, stream>>>(H1v, wv2T, bv2, s, N_ITEMS, 512, 1.0f, 0);
    linear64<<<(N_ITEMS + 15) / 16, 256, 0, stream>>>(H1t, wt2T, bt2, s, N_ITEMS, 256, 1.0f, 1);
    linear64<<<(N_ITEMS + 15) / 16, 256, 0, stream>>>(s, wdT, bd, cur0 + (size_t)N_USERS * 64,
                                                      N_ITEMS, 64, 0.5f, 0);

    // ---- assemble ego, write out[:, 0:64] ----
    ego_fill<<<(N_NODES * EMB + 255) / 256, 256, 0, stream>>>(emb, cur0, out);

    // ---- propagation layer 1 (gather SpMM, no atomics) ----
    spmm_gather<<<(N_NODES + 3) / 4, 256, 0, stream>>>(row_ptr, col_s, val_s, cur0, nb);
    concat_lin<<<(N_NODES + 15) / 16, 256, 0, stream>>>(cur0, nb, wc0T, bc0, cur1, out, 64);

    // ---- propagation layer 2 ----
    spmm_gather<<<(N_NODES + 3) / 4, 256, 0, stream>>>(row_ptr, col_s, val_s, cur1, nb);
    concat_lin<<<(N_NODES + 15) / 16, 256, 0, stream>>>(cur1, nb, wc1T, bc1, nullptr, out, 128);
}

// Round 2
// 796.995 us; speedup vs baseline: 1.6648x; 1.2647x over previous
//
#include <hip/hip_runtime.h>
#include <hip/hip_bf16.h>
#include <cstddef>

#define N_USERS 50000
#define N_ITEMS 10000
#define N_NODES 100000
#define EMB 64
#define NNZ_E 1600000
#define VIS_DIM 2048
#define TXT_DIM 300

typedef short bf16x8 __attribute__((ext_vector_type(8)));
typedef float f32x4  __attribute__((ext_vector_type(4)));

__device__ inline unsigned short f2bf(float x) {
    __hip_bfloat16 h = __float2bfloat16(x);
    return __builtin_bit_cast(unsigned short, h);
}
__device__ inline float bf2f(unsigned short u) {
    unsigned int t = ((unsigned int)u) << 16;
    float f;
    __builtin_memcpy(&f, &t, 4);
    return f;
}

// ---------------------------------------------------------------------------
// Split-precision bf16 MFMA GEMM v2: C[M,N] = act(A[M,K] @ W[N,K]^T + bias).
// TM=128, TN=128, BK=32. 256 threads = 4 waves in 2x2, each wave 64x64 as
// 4x4 frags of mfma_f32_16x16x32_bf16, 3-term split (Ah*Wh + Ah*Wl + Al*Wh).
// Register-prefetch pipeline: global loads for k0+1 issued before the MFMA
// block so memory latency overlaps compute.
// LDS rows padded 32->40 shorts (80 B).
// ---------------------------------------------------------------------------
#define GLDW 40

__global__ __launch_bounds__(256, 2) void gemm_bf3(
    const float* __restrict__ A, const float* __restrict__ W,
    const float* __restrict__ bias, float* __restrict__ C,
    int M, int N, int K, int relu)
{
    __shared__ unsigned short Ah[128][GLDW], Al[128][GLDW];
    __shared__ unsigned short Wh[128][GLDW], Wl[128][GLDW];

    const int t   = threadIdx.x;
    const int w   = t >> 6;
    const int l   = t & 63;
    const int l16 = l & 15;
    const int lq  = l >> 4;
    const int m0  = blockIdx.y * 128;
    const int n0  = blockIdx.x * 128;
    const int mh  = (w & 1) * 64;
    const int nh  = (w >> 1) * 64;

    // staging chunk map: chunk c (0..511) per matrix: row = c>>2, kc = c&3
    // thread t owns chunks {t, t+256}; 8 consecutive k-elements per chunk.
    const int r0 = t >> 2,          kc0 = t & 3;
    const int r1 = (t + 256) >> 2,  kc1 = t & 3;   // (t+256)&3 == t&3

    f32x4 acc[4][4] = {};

    const int kiters = (K + 31) / 32;

    float pa[2][8], pw[2][8];

    // ---- prologue: load tile 0 into regs ----
    {
        const int k0 = 0;
        #pragma unroll
        for (int p = 0; p < 2; p++) {
            int row = p ? r1 : r0, kc = p ? kc1 : kc0;
            int rg = m0 + row; if (rg >= M) rg = M - 1;
            const float* g = A + (size_t)rg * K + k0 + kc * 8;
            if (k0 + kc * 8 + 7 < K) {
                float4 q0 = *(const float4*)g, q1 = *(const float4*)(g + 4);
                pa[p][0]=q0.x; pa[p][1]=q0.y; pa[p][2]=q0.z; pa[p][3]=q0.w;
                pa[p][4]=q1.x; pa[p][5]=q1.y; pa[p][6]=q1.z; pa[p][7]=q1.w;
            } else {
                #pragma unroll
                for (int i = 0; i < 8; i++)
                    pa[p][i] = (k0 + kc * 8 + i < K) ? g[i] : 0.f;
            }
            int ng = n0 + row; if (ng >= N) ng = N - 1;
            const float* gw = W + (size_t)ng * K + k0 + kc * 8;
            if (k0 + kc * 8 + 7 < K) {
                float4 q0 = *(const float4*)gw, q1 = *(const float4*)(gw + 4);
                pw[p][0]=q0.x; pw[p][1]=q0.y; pw[p][2]=q0.z; pw[p][3]=q0.w;
                pw[p][4]=q1.x; pw[p][5]=q1.y; pw[p][6]=q1.z; pw[p][7]=q1.w;
            } else {
                #pragma unroll
                for (int i = 0; i < 8; i++)
                    pw[p][i] = (k0 + kc * 8 + i < K) ? gw[i] : 0.f;
            }
        }
    }

    for (int kt = 0; kt < kiters; kt++) {
        // ---- convert prefetched regs -> LDS hi/lo ----
        #pragma unroll
        for (int p = 0; p < 2; p++) {
            int row = p ? r1 : r0, kc = p ? kc1 : kc0;
            bf16x8 hi, lo;
            #pragma unroll
            for (int i = 0; i < 8; i++) {
                unsigned short h = f2bf(pa[p][i]);
                hi[i] = (short)h;
                lo[i] = (short)f2bf(pa[p][i] - bf2f(h));
            }
            *(bf16x8*)&Ah[row][kc * 8] = hi;
            *(bf16x8*)&Al[row][kc * 8] = lo;
            #pragma unroll
            for (int i = 0; i < 8; i++) {
                unsigned short h = f2bf(pw[p][i]);
                hi[i] = (short)h;
                lo[i] = (short)f2bf(pw[p][i] - bf2f(h));
            }
            *(bf16x8*)&Wh[row][kc * 8] = hi;
            *(bf16x8*)&Wl[row][kc * 8] = lo;
        }
        __syncthreads();

        // ---- issue next tile's global loads (overlap with MFMA below) ----
        if (kt + 1 < kiters) {
            const int k0 = (kt + 1) * 32;
            #pragma unroll
            for (int p = 0; p < 2; p++) {
                int row = p ? r1 : r0, kc = p ? kc1 : kc0;
                int rg = m0 + row; if (rg >= M) rg = M - 1;
                const float* g = A + (size_t)rg * K + k0 + kc * 8;
                if (k0 + kc * 8 + 7 < K) {
                    float4 q0 = *(const float4*)g, q1 = *(const float4*)(g + 4);
                    pa[p][0]=q0.x; pa[p][1]=q0.y; pa[p][2]=q0.z; pa[p][3]=q0.w;
                    pa[p][4]=q1.x; pa[p][5]=q1.y; pa[p][6]=q1.z; pa[p][7]=q1.w;
                } else {
                    #pragma unroll
                    for (int i = 0; i < 8; i++)
                        pa[p][i] = (k0 + kc * 8 + i < K) ? g[i] : 0.f;
                }
                int ng = n0 + row; if (ng >= N) ng = N - 1;
                const float* gw = W + (size_t)ng * K + k0 + kc * 8;
                if (k0 + kc * 8 + 7 < K) {
                    float4 q0 = *(const float4*)gw, q1 = *(const float4*)(gw + 4);
                    pw[p][0]=q0.x; pw[p][1]=q0.y; pw[p][2]=q0.z; pw[p][3]=q0.w;
                    pw[p][4]=q1.x; pw[p][5]=q1.y; pw[p][6]=q1.z; pw[p][7]=q1.w;
                } else {
                    #pragma unroll
                    for (int i = 0; i < 8; i++)
                        pw[p][i] = (k0 + kc * 8 + i < K) ? gw[i] : 0.f;
                }
            }
        }

        // ---- MFMA: 4x4 frags x 3 split terms ----
        {
            bf16x8 ah[4], al[4];
            #pragma unroll
            for (int mi = 0; mi < 4; mi++) {
                ah[mi] = *(const bf16x8*)&Ah[mh + mi * 16 + l16][lq * 8];
                al[mi] = *(const bf16x8*)&Al[mh + mi * 16 + l16][lq * 8];
            }
            #pragma unroll
            for (int ni = 0; ni < 4; ni++) {
                bf16x8 bh = *(const bf16x8*)&Wh[nh + ni * 16 + l16][lq * 8];
                bf16x8 bl = *(const bf16x8*)&Wl[nh + ni * 16 + l16][lq * 8];
                #pragma unroll
                for (int mi = 0; mi < 4; mi++) {
                    acc[mi][ni] = __builtin_amdgcn_mfma_f32_16x16x32_bf16(
                        ah[mi], bh, acc[mi][ni], 0, 0, 0);
                    acc[mi][ni] = __builtin_amdgcn_mfma_f32_16x16x32_bf16(
                        ah[mi], bl, acc[mi][ni], 0, 0, 0);
                    acc[mi][ni] = __builtin_amdgcn_mfma_f32_16x16x32_bf16(
                        al[mi], bh, acc[mi][ni], 0, 0, 0);
                }
            }
        }
        __syncthreads();
    }

    // ---- epilogue ----
    #pragma unroll
    for (int ni = 0; ni < 4; ni++) {
        int col = n0 + nh + ni * 16 + l16;
        float bcol = bias[col];
        #pragma unroll
        for (int mi = 0; mi < 4; mi++) {
            #pragma unroll
            for (int r = 0; r < 4; r++) {
                int row = m0 + mh + mi * 16 + lq * 4 + r;
                if (row >= M) continue;
                float v = acc[mi][ni][r] + bcol;
                if (relu) v = fmaxf(v, 0.f);
                C[(size_t)row * N + col] = v;
            }
        }
    }
}

// ---------------------------------------------------------------------------
// concat_mfma: out[M,64] = leaky_relu([cur|nb][M,128] @ Wc[64,128]^T + bias)
// Same split-bf16 3-term MFMA scheme as gemm_bf3, specialized:
//   TM=128, TN=64, BK=32, kiters=4 (k<64 from cur, k>=64 from nb).
//   4 waves stacked in M (wave tile 32x64, 2x4 frags).
//   Wc read row-major directly (no transpose kernel needed).
// Replaces the latency-bound scalar concat_lin (135us, VALUBusy 23%,
// 1 VMEM per 2 FMAs structural floor).
// ---------------------------------------------------------------------------
__global__ __launch_bounds__(256, 2) void concat_mfma(
    const float* __restrict__ cur, const float* __restrict__ nbuf,
    const float* __restrict__ Wc, const float* __restrict__ bias,
    float* __restrict__ out_cur, float* __restrict__ out_full, int col_off)
{
    __shared__ unsigned short Ah[128][GLDW], Al[128][GLDW];
    __shared__ unsigned short Bh[64][GLDW],  Bl[64][GLDW];

    const int t   = threadIdx.x;
    const int w   = t >> 6;
    const int l   = t & 63;
    const int l16 = l & 15;
    const int lq  = l >> 4;
    const int m0  = blockIdx.x * 128;
    const int mh  = w * 32;

    // staging: A has 512 chunks (rows r and r+64), B has 256 chunks (row r)
    const int r  = t >> 2;
    const int kc = t & 3;

    f32x4 acc[2][4] = {};

    float pa[2][8], pw[8];

    // ---- tile loader (K fixed = 128, BK=32, no k-tail) ----
    auto load_tile = [&](int kt) {
        const float* src = (kt < 2) ? cur : nbuf;
        const int kcol = (kt & 1) * 32 + kc * 8;
        #pragma unroll
        for (int p = 0; p < 2; p++) {
            int rg = m0 + r + p * 64;
            if (rg >= N_NODES) rg = N_NODES - 1;
            const float* g = src + (size_t)rg * 64 + kcol;
            float4 q0 = *(const float4*)g, q1 = *(const float4*)(g + 4);
            pa[p][0]=q0.x; pa[p][1]=q0.y; pa[p][2]=q0.z; pa[p][3]=q0.w;
            pa[p][4]=q1.x; pa[p][5]=q1.y; pa[p][6]=q1.z; pa[p][7]=q1.w;
        }
        const float* gw = Wc + (size_t)r * 128 + kt * 32 + kc * 8;
        float4 q0 = *(const float4*)gw, q1 = *(const float4*)(gw + 4);
        pw[0]=q0.x; pw[1]=q0.y; pw[2]=q0.z; pw[3]=q0.w;
        pw[4]=q1.x; pw[5]=q1.y; pw[6]=q1.z; pw[7]=q1.w;
    };

    load_tile(0);

    for (int kt = 0; kt < 4; kt++) {
        // ---- convert prefetched regs -> LDS hi/lo ----
        #pragma unroll
        for (int p = 0; p < 2; p++) {
            bf16x8 hi, lo;
            #pragma unroll
            for (int i = 0; i < 8; i++) {
                unsigned short h = f2bf(pa[p][i]);
                hi[i] = (short)h;
                lo[i] = (short)f2bf(pa[p][i] - bf2f(h));
            }
            *(bf16x8*)&Ah[r + p * 64][kc * 8] = hi;
            *(bf16x8*)&Al[r + p * 64][kc * 8] = lo;
        }
        {
            bf16x8 hi, lo;
            #pragma unroll
            for (int i = 0; i < 8; i++) {
                unsigned short h = f2bf(pw[i]);
                hi[i] = (short)h;
                lo[i] = (short)f2bf(pw[i] - bf2f(h));
            }
            *(bf16x8*)&Bh[r][kc * 8] = hi;
            *(bf16x8*)&Bl[r][kc * 8] = lo;
        }
        __syncthreads();

        if (kt < 3) load_tile(kt + 1);

        // ---- MFMA: 2x4 frags x 3 split terms ----
        {
            bf16x8 ah[2], al[2];
            #pragma unroll
            for (int mi = 0; mi < 2; mi++) {
                ah[mi] = *(const bf16x8*)&Ah[mh + mi * 16 + l16][lq * 8];
                al[mi] = *(const bf16x8*)&Al[mh + mi * 16 + l16][lq * 8];
            }
            #pragma unroll
            for (int ni = 0; ni < 4; ni++) {
                bf16x8 bh = *(const bf16x8*)&Bh[ni * 16 + l16][lq * 8];
                bf16x8 bl = *(const bf16x8*)&Bl[ni * 16 + l16][lq * 8];
                #pragma unroll
                for (int mi = 0; mi < 2; mi++) {
                    acc[mi][ni] = __builtin_amdgcn_mfma_f32_16x16x32_bf16(
                        ah[mi], bh, acc[mi][ni], 0, 0, 0);
                    acc[mi][ni] = __builtin_amdgcn_mfma_f32_16x16x32_bf16(
                        ah[mi], bl, acc[mi][ni], 0, 0, 0);
                    acc[mi][ni] = __builtin_amdgcn_mfma_f32_16x16x32_bf16(
                        al[mi], bh, acc[mi][ni], 0, 0, 0);
                }
            }
        }
        __syncthreads();
    }

    // ---- epilogue: bias + leaky_relu, write out_cur and out_full ----
    #pragma unroll
    for (int ni = 0; ni < 4; ni++) {
        int col = ni * 16 + l16;
        float bcol = bias[col];
        #pragma unroll
        for (int mi = 0; mi < 2; mi++) {
            #pragma unroll
            for (int rr = 0; rr < 4; rr++) {
                int row = m0 + mh + mi * 16 + lq * 4 + rr;
                if (row >= N_NODES) continue;
                float v = acc[mi][ni][rr] + bcol;
                v = (v > 0.f) ? v : 0.01f * v;
                if (out_cur) out_cur[(size_t)row * 64 + col] = v;
                out_full[(size_t)row * 192 + col_off + col] = v;
            }
        }
    }
}

// ---------------------------------------------------------------------------
__global__ void transp64(const float* __restrict__ W, float* __restrict__ wT, int K)
{
    int i = blockIdx.x * 256 + threadIdx.x;
    if (i >= 64 * K) return;
    int d = i / K, k = i - d * K;
    wT[k * 64 + d] = W[i];
}

// ---------------------------------------------------------------------------
// linear64 v2: out[M,64] = in[M,K] @ wT[K,64] * in_scale + bias  (opt. +=)
// 4 rows per wave, 16 rows per block, float4 x-loads + 8 wT loads per k-step,
// 4 independent accumulators.
// ---------------------------------------------------------------------------
__global__ __launch_bounds__(256) void linear64(
    const float* __restrict__ in, const float* __restrict__ wT,
    const float* __restrict__ bias, float* __restrict__ out,
    int M, int K, float in_scale, int add)
{
    int t  = threadIdx.x;
    int d  = t & 63;
    int w  = t >> 6;
    int m0 = blockIdx.x * 16 + w * 4;
    if (m0 >= M) return;
    int mlast = M - 1;
    int m1 = (m0 + 1 < M) ? m0 + 1 : mlast;
    int m2 = (m0 + 2 < M) ? m0 + 2 : mlast;
    int m3 = (m0 + 3 < M) ? m0 + 3 : mlast;

    const float* x0 = in + (size_t)m0 * K;
    const float* x1 = in + (size_t)m1 * K;
    const float* x2 = in + (size_t)m2 * K;
    const float* x3 = in + (size_t)m3 * K;

    float a0 = 0.f, a1 = 0.f, a2 = 0.f, a3 = 0.f;

    for (int k = 0; k < K; k += 8) {
        const float* wp = wT + (size_t)k * 64 + d;
        float w0 = wp[0],   w1 = wp[64],  w2 = wp[128], w3 = wp[192];
        float w4 = wp[256], w5 = wp[320], w6 = wp[384], w7 = wp[448];
        float4 p0 = *(const float4*)(x0 + k), q0 = *(const float4*)(x0 + k + 4);
        float4 p1 = *(const float4*)(x1 + k), q1 = *(const float4*)(x1 + k + 4);
        float4 p2 = *(const float4*)(x2 + k), q2 = *(const float4*)(x2 + k + 4);
        float4 p3 = *(const float4*)(x3 + k), q3 = *(const float4*)(x3 + k + 4);
        a0 += p0.x*w0 + p0.y*w1 + p0.z*w2 + p0.w*w3
            + q0.x*w4 + q0.y*w5 + q0.z*w6 + q0.w*w7;
        a1 += p1.x*w0 + p1.y*w1 + p1.z*w2 + p1.w*w3
            + q1.x*w4 + q1.y*w5 + q1.z*w6 + q1.w*w7;
        a2 += p2.x*w0 + p2.y*w1 + p2.z*w2 + p2.w*w3
            + q2.x*w4 + q2.y*w5 + q2.z*w6 + q2.w*w7;
        a3 += p3.x*w0 + p3.y*w1 + p3.z*w2 + p3.w*w3
            + q3.x*w4 + q3.y*w5 + q3.z*w6 + q3.w*w7;
    }

    float b = bias[d];
    float r0 = a0 * in_scale + b;
    float r1 = a1 * in_scale + b;
    float r2 = a2 * in_scale + b;
    float r3 = a3 * in_scale + b;
    if (add) {
        out[(size_t)m0 * 64 + d] += r0;
        if (m0 + 1 < M) out[(size_t)m1 * 64 + d] += r1;
        if (m0 + 2 < M) out[(size_t)m2 * 64 + d] += r2;
        if (m0 + 3 < M) out[(size_t)m3 * 64 + d] += r3;
    } else {
        out[(size_t)m0 * 64 + d] = r0;
        if (m0 + 1 < M) out[(size_t)m1 * 64 + d] = r1;
        if (m0 + 2 < M) out[(size_t)m2 * 64 + d] = r2;
        if (m0 + 3 < M) out[(size_t)m3 * 64 + d] = r3;
    }
}

// ---------------------------------------------------------------------------
__global__ void ego_fill(const float* __restrict__ emb, float* __restrict__ cur0,
                         float* __restrict__ out_full)
{
    int tid = blockIdx.x * 256 + threadIdx.x;
    if (tid >= N_NODES * EMB) return;
    int m = tid >> 6, d = tid & 63;
    float v;
    if (m < N_USERS || m >= N_USERS + N_ITEMS) {
        v = emb[tid];
        cur0[tid] = v;
    } else {
        v = cur0[tid];
    }
    out_full[(size_t)m * 192 + d] = v;
}

// ---------------------------------------------------------------------------
// CSR build: histogram -> exclusive scan -> scatter
// ---------------------------------------------------------------------------
__global__ __launch_bounds__(256) void hist_rows(
    const int* __restrict__ row, int* __restrict__ cnt, int nnz)
{
    int e = blockIdx.x * 256 + threadIdx.x;
    if (e >= nnz) return;
    atomicAdd(&cnt[row[e]], 1);
}

__global__ __launch_bounds__(256) void scan1(int* __restrict__ cnt,
                                             int* __restrict__ bsum, int n)
{
    __shared__ int part[256];
    int t = threadIdx.x;
    int base = blockIdx.x * 1024 + t * 4;
    int v0 = 0, v1 = 0, v2 = 0, v3 = 0;
    if (base + 0 < n) v0 = cnt[base + 0];
    if (base + 1 < n) v1 = cnt[base + 1];
    if (base + 2 < n) v2 = cnt[base + 2];
    if (base + 3 < n) v3 = cnt[base + 3];
    int s = v0 + v1 + v2 + v3;
    part[t] = s;
    __syncthreads();
    for (int off = 1; off < 256; off <<= 1) {
        int x = (t >= off) ? part[t - off] : 0;
        __syncthreads();
        part[t] += x;
        __syncthreads();
    }
    int excl = part[t] - s;
    if (t == 255) bsum[blockIdx.x] = part[t];
    if (base + 0 < n) cnt[base + 0] = excl;
    if (base + 1 < n) cnt[base + 1] = excl + v0;
    if (base + 2 < n) cnt[base + 2] = excl + v0 + v1;
    if (base + 3 < n) cnt[base + 3] = excl + v0 + v1 + v2;
}

__global__ void scan2(int* __restrict__ bsum, int nb)
{
    if (threadIdx.x == 0 && blockIdx.x == 0) {
        int acc = 0;
        for (int i = 0; i < nb; i++) { int v = bsum[i]; bsum[i] = acc; acc += v; }
    }
}

__global__ __launch_bounds__(256) void scan3(
    const int* __restrict__ excl, const int* __restrict__ bsum,
    int* __restrict__ row_ptr, int* __restrict__ row_cur, int n, int nnz)
{
    int i = blockIdx.x * 256 + threadIdx.x;
    if (i > n) return;
    if (i == n) { row_ptr[n] = nnz; return; }
    int v = excl[i] + bsum[i >> 10];
    row_ptr[i] = v;
    row_cur[i] = v;
}

__global__ __launch_bounds__(256) void scatter_csr(
    const int* __restrict__ row, const int* __restrict__ col,
    const float* __restrict__ val, int* __restrict__ row_cur,
    int* __restrict__ col_s, float* __restrict__ val_s, int nnz)
{
    int e = blockIdx.x * 256 + threadIdx.x;
    if (e >= nnz) return;
    int r = row[e];
    int p = atomicAdd(&row_cur[r], 1);
    col_s[p] = col[e];
    val_s[p] = val[e];
}

// ---------------------------------------------------------------------------
// Gather SpMM v2: one wave per row; 64 lanes = 4 edge-slots x 16 dim-groups.
// float4 gathers, 4 edges in flight, shuffle-xor reduce across edge slots.
// ---------------------------------------------------------------------------
__global__ __launch_bounds__(256) void spmm_gather(
    const int* __restrict__ row_ptr, const int* __restrict__ col_s,
    const float* __restrict__ val_s, const float* __restrict__ cur,
    float* __restrict__ nb)
{
    int t  = threadIdx.x;
    int wv = t >> 6;
    int l  = t & 63;
    int eg = l >> 4;          // edge slot 0..3
    int dg = l & 15;          // dim group (4 floats)
    int m = blockIdx.x * 4 + wv;
    if (m >= N_NODES) return;
    int beg = row_ptr[m], end = row_ptr[m + 1];
    float ax = 0.f, ay = 0.f, az = 0.f, aw = 0.f;
    for (int j = beg + eg; j < end; j += 4) {
        int   c = col_s[j];
        float v = val_s[j];
        float4 cv = *(const float4*)&cur[(size_t)c * 64 + dg * 4];
        ax += v * cv.x; ay += v * cv.y; az += v * cv.z; aw += v * cv.w;
    }
    ax += __shfl_xor(ax, 16, 64); ay += __shfl_xor(ay, 16, 64);
    az += __shfl_xor(az, 16, 64); aw += __shfl_xor(aw, 16, 64);
    ax += __shfl_xor(ax, 32, 64); ay += __shfl_xor(ay, 32, 64);
    az += __shfl_xor(az, 32, 64); aw += __shfl_xor(aw, 32, 64);
    if (eg == 0) {
        float4 r; r.x = ax; r.y = ay; r.z = az; r.w = aw;
        *(float4*)&nb[(size_t)m * 64 + dg * 4] = r;
    }
}

// ---------------------------------------------------------------------------
extern "C" void kernel_launch(void* const* d_in, const int* in_sizes, int n_in,
                              void* d_out, int out_size, void* d_ws, size_t ws_size,
                              hipStream_t stream)
{
    const int*   adj_row = (const int*)  d_in[0];
    const int*   adj_col = (const int*)  d_in[1];
    const float* adj_val = (const float*)d_in[2];
    const float* emb     = (const float*)d_in[3];
    const float* visf    = (const float*)d_in[4];
    const float* txtf    = (const float*)d_in[5];
    const float* Wv1 = (const float*)d_in[6];  const float* bv1 = (const float*)d_in[7];
    const float* Wv2 = (const float*)d_in[8];  const float* bv2 = (const float*)d_in[9];
    const float* Wt1 = (const float*)d_in[10]; const float* bt1 = (const float*)d_in[11];
    const float* Wt2 = (const float*)d_in[12]; const float* bt2 = (const float*)d_in[13];
    const float* Wd  = (const float*)d_in[14]; const float* bd  = (const float*)d_in[15];
    const float* Wc0 = (const float*)d_in[16]; const float* bc0 = (const float*)d_in[17];
    const float* Wc1 = (const float*)d_in[18]; const float* bc1 = (const float*)d_in[19];

    float* out = (float*)d_out;
    float* ws  = (float*)d_ws;

    // workspace layout (float offsets) — unchanged from R2 (proven size)
    float* H1v  = ws + 0;          // 10000*512
    float* H1t  = ws + 5120000;    // 10000*256
    float* nb   = ws + 0;          // 100000*64 (reuses H1v/H1t region)
    float* s    = ws + 7680000;    // 10000*64
    float* cur0 = ws + 8320000;    // 100000*64
    float* cur1 = ws + 14720000;   // 100000*64
    float* wv2T = ws + 21120000;   // 512*64
    float* wt2T = wv2T + 32768;    // 256*64
    float* wdT  = wt2T + 16384;    // 64*64
    int*   col_s   = (int*)  (ws + 21200000);  // 1.6M
    float* val_s   =          ws + 22800000;   // 1.6M
    int*   row_ptr = (int*)  (ws + 24400000);  // 100001
    int*   row_cur = (int*)  (ws + 24510000);  // 100000
    int*   cnt     = (int*)  (ws + 24620000);  // 100000
    int*   bsum    = (int*)  (ws + 24730000);  // 98

    const int NBLK = (N_NODES + 1023) / 1024;  // 98

    // ---- weight transposes (tiny; Wc0/Wc1 no longer need transposing) ----
    transp64<<<(64 * 512 + 255) / 256, 256, 0, stream>>>(Wv2, wv2T, 512);
    transp64<<<(64 * 256 + 255) / 256, 256, 0, stream>>>(Wt2, wt2T, 256);
    transp64<<<(64 * 64  + 255) / 256, 256, 0, stream>>>(Wd,  wdT,  64);

    // ---- CSR build (reused for both propagation layers) ----
    hipMemsetAsync(cnt, 0, N_NODES * sizeof(int), stream);
    hist_rows<<<(NNZ_E + 255) / 256, 256, 0, stream>>>(adj_row, cnt, NNZ_E);
    scan1<<<NBLK, 256, 0, stream>>>(cnt, bsum, N_NODES);
    scan2<<<1, 64, 0, stream>>>(bsum, NBLK);
    scan3<<<(N_NODES + 256) / 256, 256, 0, stream>>>(cnt, bsum, row_ptr, row_cur,
                                                     N_NODES, NNZ_E);
    scatter_csr<<<(NNZ_E + 255) / 256, 256, 0, stream>>>(adj_row, adj_col, adj_val,
                                                         row_cur, col_s, val_s, NNZ_E);

    // ---- item MLP layer 1: pipelined split-bf16 MFMA GEMMs ----
    {
        dim3 g(512 / 128, (N_ITEMS + 127) / 128);
        gemm_bf3<<<g, 256, 0, stream>>>(visf, Wv1, bv1, H1v, N_ITEMS, 512, VIS_DIM, 1);
    }
    {
        dim3 g(256 / 128, (N_ITEMS + 127) / 128);
        gemm_bf3<<<g, 256, 0, stream>>>(txtf, Wt1, bt1, H1t, N_ITEMS, 256, TXT_DIM, 1);
    }

    // ---- layer 2 + shared Wd:  fused = (0.5*(vis2+txt2)) @ Wd^T + bd ----
    linear64<<<(N_ITEMS + 15) / 16, 256, 0, stream>>>(H1v, wv2T, bv2, s, N_ITEMS, 512, 1.0f, 0);
    linear64<<<(N_ITEMS + 15) / 16, 256, 0, stream>>>(H1t, wt2T, bt2, s, N_ITEMS, 256, 1.0f, 1);
    linear64<<<(N_ITEMS + 15) / 16, 256, 0, stream>>>(s, wdT, bd, cur0 + (size_t)N_USERS * 64,
                                                      N_ITEMS, 64, 0.5f, 0);

    // ---- assemble ego, write out[:, 0:64] ----
    ego_fill<<<(N_NODES * EMB + 255) / 256, 256, 0, stream>>>(emb, cur0, out);

    // ---- propagation layer 1 (gather SpMM + MFMA concat-linear) ----
    spmm_gather<<<(N_NODES + 3) / 4, 256, 0, stream>>>(row_ptr, col_s, val_s, cur0, nb);
    concat_mfma<<<(N_NODES + 127) / 128, 256, 0, stream>>>(cur0, nb, Wc0, bc0, cur1, out, 64);

    // ---- propagation layer 2 ----
    spmm_gather<<<(N_NODES + 3) / 4, 256, 0, stream>>>(row_ptr, col_s, val_s, cur1, nb);
    concat_mfma<<<(N_NODES + 127) / 128, 256, 0, stream>>>(cur1, nb, Wc1, bc1, nullptr, out, 128);
}